// Round 7
// baseline (1175.203 us; speedup 1.0000x reference)
//
#include <hip/hip_runtime.h>
#include <hip/hip_bf16.h>
#include <cstdint>
#include <cstddef>

#define NB 16
#define LATD 256
#define DMODEL 256
#define DIN 512
#define DSTATE 16
#define DTRANK 16
#define SEQ 1024
#define KCONV 4
#define NOUT 64
#define NLAYER 4
#define NTOK (NB*SEQ)   // 16384
#define GCH 64          // scan chunks (64 -> 2048 blocks, 8/CU)
#define CLEN (SEQ/GCH)  // 16 steps per chunk
#define LOG2E 1.4426950408889634f

typedef __attribute__((ext_vector_type(8))) short short8;
typedef __attribute__((ext_vector_type(4))) float f32x4;

__device__ __forceinline__ float sigmoidf_(float x){ return 1.f/(1.f+__expf(-x)); }
__device__ __forceinline__ short bf16s(float x){ __hip_bfloat16 h = __float2bfloat16(x); return *(short*)&h; }
__device__ __forceinline__ float softplusf_(float x){ return (x > 20.f) ? x : __logf(1.f + __expf(x)); }

__device__ __forceinline__ void gl_lds16(const void* g, void* l) {
  __builtin_amdgcn_global_load_lds((const __attribute__((address_space(1))) void*)g,
                                   (__attribute__((address_space(3))) void*)l,
                                   16, 0, 0);
}

// ---------------- latent head: base = gelu(LN(z) @ latent_w.T + latent_bias) ----------------
__global__ void latent_kernel(const float* __restrict__ z,
                              const float* __restrict__ lg, const float* __restrict__ lb,
                              const float* __restrict__ lw, const float* __restrict__ lbias,
                              float* __restrict__ base)
{
  int b = blockIdx.x;          // 16
  int tid = threadIdx.x;       // 256
  __shared__ float zn[LATD];
  __shared__ float red[8];
  float v = z[b*LATD + tid];
  float s = v;
  #pragma unroll
  for (int off=32; off; off>>=1) s += __shfl_xor(s, off);
  if ((tid & 63)==0) red[tid>>6] = s;
  __syncthreads();
  float mu = (red[0]+red[1]+red[2]+red[3]) * (1.f/LATD);
  float dvi = v - mu;
  float s2 = dvi*dvi;
  #pragma unroll
  for (int off=32; off; off>>=1) s2 += __shfl_xor(s2, off);
  if ((tid & 63)==0) red[4 + (tid>>6)] = s2;
  __syncthreads();
  float var = (red[4]+red[5]+red[6]+red[7]) * (1.f/LATD);
  float rs = rsqrtf(var + 1e-5f);
  zn[tid] = dvi*rs*lg[tid] + lb[tid];
  __syncthreads();
  const float* wrow = &lw[(size_t)tid*LATD];
  float acc = lbias[tid];
  #pragma unroll 4
  for (int l=0; l<LATD; ++l) acc += zn[l]*wrow[l];
  float g = 0.5f*acc*(1.f + erff(acc*0.70710678118654752f));   // exact gelu
  base[b*DMODEL + tid] = g;
}

// ---------------- h = base[:,None,:] + time_emb[None] ----------------
__global__ void addtime_kernel(const float* __restrict__ base, const float* __restrict__ temb,
                               float* __restrict__ h)
{
  int idx = blockIdx.x*256 + threadIdx.x;  // over NTOK*DMODEL
  int dd = idx & (DMODEL-1);
  int t = (idx >> 8) & (SEQ-1);
  int bb = idx >> 18;
  h[idx] = base[bb*DMODEL + dd] + temb[t*DMODEL + dd];
}

// ---------------- per-token LayerNorm; 4 tokens/block (1 wave each); OUTBF=1 -> bf16 --------
template<int OUTBF>
__global__ void ln_kernel(const float* __restrict__ x, const float* __restrict__ g,
                          const float* __restrict__ b, void* __restrict__ outp)
{
  int n = blockIdx.x*4 + (threadIdx.x >> 6);
  int lane = threadIdx.x & 63;
  const float4 v = ((const float4*)&x[(size_t)n*DMODEL])[lane];
  float s = v.x+v.y+v.z+v.w;
  #pragma unroll
  for (int off=32; off; off>>=1) s += __shfl_xor(s, off);
  float mu = s * (1.f/DMODEL);
  float dx = v.x-mu, dy = v.y-mu, dz = v.z-mu, dw = v.w-mu;
  float s2 = dx*dx+dy*dy+dz*dz+dw*dw;
  #pragma unroll
  for (int off=32; off; off>>=1) s2 += __shfl_xor(s2, off);
  float rs = rsqrtf(s2*(1.f/DMODEL) + 1e-5f);
  const float4 gv = ((const float4*)g)[lane];
  const float4 bv = ((const float4*)b)[lane];
  float o0 = dx*rs*gv.x + bv.x;
  float o1 = dy*rs*gv.y + bv.y;
  float o2 = dz*rs*gv.z + bv.z;
  float o3 = dw*rs*gv.w + bv.w;
  if (OUTBF) {
    __hip_bfloat16* o = (__hip_bfloat16*)outp + (size_t)n*DMODEL + lane*4;
    o[0] = __float2bfloat16(o0); o[1] = __float2bfloat16(o1);
    o[2] = __float2bfloat16(o2); o[3] = __float2bfloat16(o3);
  } else {
    float4 o; o.x=o0; o.y=o1; o.z=o2; o.w=o3;
    ((float4*)((float*)outp + (size_t)n*DMODEL))[lane] = o;
  }
}

// ---------------- fp32 → bf16 cast ----------------
__global__ void castbf_kernel(const float* __restrict__ in, __hip_bfloat16* __restrict__ out, int n)
{
  int i = blockIdx.x*256 + threadIdx.x;
  if (i < n) out[i] = __float2bfloat16(in[i]);
}

// ---------------- bf16 MFMA GEMM: C[N,M] = A[N,K] @ W[M,K]^T (+bias) (+C if ACCUM) ----------
template<int ACCUM>
__global__ void gemm_bf16(const __hip_bfloat16* __restrict__ A,
                          const __hip_bfloat16* __restrict__ W,
                          const float* __restrict__ bias, float* __restrict__ C,
                          int N, int M, int K)
{
  __shared__ __hip_bfloat16 As[128*32];   // row-major, 32 bf16 (64B) per row, NO padding
  __shared__ __hip_bfloat16 Ws[128*32];
  int tid = threadIdx.x;
  int lane = tid & 63, w = tid >> 6;
  int wr = w >> 1, wc = w & 1;
  int n0 = blockIdx.x * 128, m0 = blockIdx.y * 128;
  int mrow = lane & 15, q = lane >> 4;
  f32x4 acc[4][4] = {};
  for (int k0 = 0; k0 < K; k0 += 32) {
    __syncthreads();
    #pragma unroll
    for (int j = 0; j < 2; ++j) {
      int c = (w*2 + j)*64 + lane;       // chunk 0..511 of the 8KB tile
      int r = c >> 2, cq = c & 3;        // row, 16B-chunk within row
      gl_lds16(A + (size_t)(n0 + r)*K + k0 + cq*8, (char*)As + (w*2+j)*1024);
      gl_lds16(W + (size_t)(m0 + r)*K + k0 + cq*8, (char*)Ws + (w*2+j)*1024);
    }
    __syncthreads();
    short8 af[4], bfr[4];
    #pragma unroll
    for (int t = 0; t < 4; ++t) {
      af[t]  = *(const short8*)(As + ((wr*64 + t*16 + mrow)*32 + q*8));
      bfr[t] = *(const short8*)(Ws + ((wc*64 + t*16 + mrow)*32 + q*8));
    }
    #pragma unroll
    for (int i = 0; i < 4; ++i)
      #pragma unroll
      for (int jj = 0; jj < 4; ++jj)
        acc[i][jj] = __builtin_amdgcn_mfma_f32_16x16x32_bf16(af[i], bfr[jj], acc[i][jj], 0, 0, 0);
  }
  int rq = lane >> 4, cl = lane & 15;
  #pragma unroll
  for (int i = 0; i < 4; ++i) {
    int n_base = n0 + wr*64 + i*16 + rq*4;
    #pragma unroll
    for (int jj = 0; jj < 4; ++jj) {
      int m = m0 + wc*64 + jj*16 + cl;
      float bv = bias ? bias[m] : 0.f;
      #pragma unroll
      for (int r = 0; r < 4; ++r) {
        size_t o = (size_t)(n_base + r)*M + m;
        float v = acc[i][jj][r] + bv;
        if (ACCUM) v += C[o];
        C[o] = v;
      }
    }
  }
}

// ---------------- small-M MFMA GEMM: C[N, MT*16] = A[N, KT*32] @ W^T (+bias) ----------------
template<int MT, int KT>
__global__ void gemm_smallm(const float* __restrict__ A, const __hip_bfloat16* __restrict__ Wg,
                            const float* __restrict__ bias, float* __restrict__ C)
{
  constexpr int M = MT*16, K = KT*32;
  __shared__ __hip_bfloat16 Ws[MT*KT*64*8];
  int tid = threadIdx.x;
  #pragma unroll
  for (int c = tid; c < MT*KT*64; c += 256) {
    int lane = c & 63;
    int kt = (c >> 6) % KT;
    int mt = (c >> 6) / KT;
    int row = mt*16 + (lane & 15);
    int k   = kt*32 + (lane >> 4)*8;
    *(short8*)(Ws + (size_t)c*8) = *(const short8*)(Wg + (size_t)row*K + k);
  }
  __syncthreads();
  int lane = tid & 63, w = tid >> 6;
  int n0 = blockIdx.x*64 + w*16;
  int r = lane & 15, q = lane >> 4;
  const float* Ap = A + (size_t)(n0 + r)*K + q*8;
  f32x4 acc[MT] = {};
  for (int kt = 0; kt < KT; ++kt) {
    float4 a0 = *(const float4*)(Ap);
    float4 a1 = *(const float4*)(Ap + 4);
    Ap += 32;
    short8 af;
    af[0]=bf16s(a0.x); af[1]=bf16s(a0.y); af[2]=bf16s(a0.z); af[3]=bf16s(a0.w);
    af[4]=bf16s(a1.x); af[5]=bf16s(a1.y); af[6]=bf16s(a1.z); af[7]=bf16s(a1.w);
    #pragma unroll
    for (int mt = 0; mt < MT; ++mt) {
      short8 bfr = *(const short8*)(Ws + ((size_t)(mt*KT + kt)*64 + lane)*8);
      acc[mt] = __builtin_amdgcn_mfma_f32_16x16x32_bf16(af, bfr, acc[mt], 0, 0, 0);
    }
  }
  #pragma unroll
  for (int mt = 0; mt < MT; ++mt) {
    float bv = bias ? bias[mt*16 + r] : 0.f;
    #pragma unroll
    for (int rr = 0; rr < 4; ++rr)
      C[(size_t)(n0 + q*4 + rr)*M + mt*16 + r] = acc[mt][rr] + bv;
  }
}

// ---------------- depthwise causal conv (K=4) + bias + SiLU ----------------
__global__ void conv_kernel(const float* __restrict__ xz, const float* __restrict__ cw,
                            const float* __restrict__ cb, float* __restrict__ xs)
{
  int idx = blockIdx.x*256 + threadIdx.x; // (n,d) over NTOK*DIN
  int d = idx & (DIN-1);
  int n = idx >> 9;
  int t = n & (SEQ-1);
  const float* w = &cw[d*KCONV];
  float acc = cb[d];
  #pragma unroll
  for (int j = 0; j < KCONV; ++j) {
    if (t - j >= 0) acc = fmaf(xz[(size_t)(n-j)*(2*DIN) + d], w[KCONV-1-j], acc);
  }
  xs[idx] = acc * sigmoidf_(acc);
}

// ================= chunked parallel scan (dt-projection fused; GCH=64) =================
// dt[n,d] = softplus(dot16(dbc[n,:16], dtw[d,:]) + dtb[d]) computed inline in both passes.
// p = exp2(dtv * a2[s]) with a2 = -exp(A_log)*log2(e) pre-scaled at setup.
__global__ void scan1_kernel(const float* __restrict__ xs, const float* __restrict__ dbc,
                             const float* __restrict__ Alog,
                             const float* __restrict__ dtw, const float* __restrict__ dtbias,
                             float* __restrict__ hstate, float* __restrict__ xz)
{
  int tid = blockIdx.x*256 + threadIdx.x;  // GCH*NB*DIN = 524288
  int d = tid & (DIN-1);
  int b = (tid >> 9) & (NB-1);
  int g = tid >> 13;
  float a2[16], h[16], P[16], wdt[16];
  const float4* A4 = (const float4*)&Alog[d*DSTATE];
  const float4* W4 = (const float4*)&dtw[d*DTRANK];
  #pragma unroll
  for (int i=0;i<4;++i){
    float4 v = A4[i];
    a2[4*i+0]=-__expf(v.x)*LOG2E; a2[4*i+1]=-__expf(v.y)*LOG2E;
    a2[4*i+2]=-__expf(v.z)*LOG2E; a2[4*i+3]=-__expf(v.w)*LOG2E;
    float4 wv = W4[i];
    wdt[4*i]=wv.x; wdt[4*i+1]=wv.y; wdt[4*i+2]=wv.z; wdt[4*i+3]=wv.w;
  }
  float bdt = dtbias[d];
  #pragma unroll
  for (int s=0;s<16;++s){ h[s]=0.f; P[s]=0.f; }   // P accumulated in log2 domain
  int t0 = g*CLEN;
  size_t off  = ((size_t)b*SEQ + t0)*DIN + d;
  size_t boff = ((size_t)b*SEQ + t0)*48;
  for (int t=0;t<CLEN;++t){
    float xv = xs[off];
    const float4* R4 = (const float4*)&dbc[boff];
    float4 r0 = R4[0], r1 = R4[1], r2 = R4[2], r3 = R4[3];
    float ac0 = fmaf(r0.x, wdt[0], bdt), ac1 = r0.y*wdt[1], ac2 = r0.z*wdt[2], ac3 = r0.w*wdt[3];
    ac0 = fmaf(r1.x, wdt[4], ac0); ac1 = fmaf(r1.y, wdt[5], ac1);
    ac2 = fmaf(r1.z, wdt[6], ac2); ac3 = fmaf(r1.w, wdt[7], ac3);
    ac0 = fmaf(r2.x, wdt[8], ac0); ac1 = fmaf(r2.y, wdt[9], ac1);
    ac2 = fmaf(r2.z, wdt[10], ac2); ac3 = fmaf(r2.w, wdt[11], ac3);
    ac0 = fmaf(r3.x, wdt[12], ac0); ac1 = fmaf(r3.y, wdt[13], ac1);
    ac2 = fmaf(r3.z, wdt[14], ac2); ac3 = fmaf(r3.w, wdt[15], ac3);
    float dtv = softplusf_((ac0+ac1)+(ac2+ac3));
    float q = dtv*xv;
    const float4* B4 = (const float4*)&dbc[boff + DTRANK];
    float Bv[16];
    #pragma unroll
    for (int i=0;i<4;++i){ float4 v=B4[i]; Bv[4*i]=v.x; Bv[4*i+1]=v.y; Bv[4*i+2]=v.z; Bv[4*i+3]=v.w; }
    #pragma unroll
    for (int s=0;s<16;++s){
      float e = dtv*a2[s];
      float p = exp2f(e);
      P[s] += e;
      h[s] = fmaf(p, h[s], q*Bv[s]);
    }
    off += DIN; boff += 48;
  }
  float4* H4 = (float4*)&hstate[(size_t)tid*16];
  #pragma unroll
  for (int i=0;i<4;++i) H4[i] = make_float4(h[4*i],h[4*i+1],h[4*i+2],h[4*i+3]);
  size_t pbase = (size_t)tid*16;
  #pragma unroll
  for (int s=0;s<16;++s){ size_t i=pbase+s; xz[(i>>9)*1024 + (i&511)] = exp2f(P[s]); }
}

__global__ void scan2_kernel(float* __restrict__ hstate, const float* __restrict__ xz)
{
  int tid = blockIdx.x*256 + threadIdx.x;  // NB*DIN*16 = 131072
  float hin = 0.f;
  size_t idx = (size_t)tid;
  for (int g=0; g<GCH; ++g){
    float P  = xz[(idx>>9)*1024 + (idx&511)];
    float hl = hstate[idx];
    hstate[idx] = hin;               // becomes initial state for chunk g
    hin = fmaf(P, hin, hl);
    idx += (size_t)NB*DIN*16;
  }
}

__global__ void scan3_kernel(const float* __restrict__ dbc, const float* __restrict__ xz,
                             const float* __restrict__ Alog,
                             const float* __restrict__ dtw, const float* __restrict__ dtbias,
                             const float* __restrict__ Dp, const float* __restrict__ hstate,
                             const float* __restrict__ xs, __hip_bfloat16* __restrict__ yout)
{
  int tid = blockIdx.x*256 + threadIdx.x;  // 524288
  int d = tid & (DIN-1);
  int b = (tid >> 9) & (NB-1);
  int g = tid >> 13;
  float a2[16], h[16], wdt[16];
  const float4* A4 = (const float4*)&Alog[d*DSTATE];
  const float4* W4 = (const float4*)&dtw[d*DTRANK];
  #pragma unroll
  for (int i=0;i<4;++i){
    float4 v = A4[i];
    a2[4*i+0]=-__expf(v.x)*LOG2E; a2[4*i+1]=-__expf(v.y)*LOG2E;
    a2[4*i+2]=-__expf(v.z)*LOG2E; a2[4*i+3]=-__expf(v.w)*LOG2E;
    float4 wv = W4[i];
    wdt[4*i]=wv.x; wdt[4*i+1]=wv.y; wdt[4*i+2]=wv.z; wdt[4*i+3]=wv.w;
  }
  float bdt = dtbias[d];
  const float4* H4 = (const float4*)&hstate[(size_t)tid*16];
  #pragma unroll
  for (int i=0;i<4;++i){ float4 v=H4[i]; h[4*i]=v.x; h[4*i+1]=v.y; h[4*i+2]=v.z; h[4*i+3]=v.w; }
  float dp = Dp[d];
  int t0 = g*CLEN;
  size_t off  = ((size_t)b*SEQ + t0)*DIN + d;
  size_t boff = ((size_t)b*SEQ + t0)*48;
  size_t zoff = ((size_t)b*SEQ + t0)*(2*DIN) + DIN + d;
  for (int t=0;t<CLEN;++t){
    float xv = xs[off];
    const float4* R4 = (const float4*)&dbc[boff];
    float4 r0 = R4[0], r1 = R4[1], r2 = R4[2], r3 = R4[3];
    float ac0 = fmaf(r0.x, wdt[0], bdt), ac1 = r0.y*wdt[1], ac2 = r0.z*wdt[2], ac3 = r0.w*wdt[3];
    ac0 = fmaf(r1.x, wdt[4], ac0); ac1 = fmaf(r1.y, wdt[5], ac1);
    ac2 = fmaf(r1.z, wdt[6], ac2); ac3 = fmaf(r1.w, wdt[7], ac3);
    ac0 = fmaf(r2.x, wdt[8], ac0); ac1 = fmaf(r2.y, wdt[9], ac1);
    ac2 = fmaf(r2.z, wdt[10], ac2); ac3 = fmaf(r2.w, wdt[11], ac3);
    ac0 = fmaf(r3.x, wdt[12], ac0); ac1 = fmaf(r3.y, wdt[13], ac1);
    ac2 = fmaf(r3.z, wdt[14], ac2); ac3 = fmaf(r3.w, wdt[15], ac3);
    float dtv = softplusf_((ac0+ac1)+(ac2+ac3));
    float q = dtv*xv;
    const float4* B4 = (const float4*)&dbc[boff + DTRANK];
    const float4* C4 = (const float4*)&dbc[boff + DTRANK + DSTATE];
    float Bv[16], Cv[16];
    #pragma unroll
    for (int i=0;i<4;++i){
      float4 v=B4[i]; Bv[4*i]=v.x; Bv[4*i+1]=v.y; Bv[4*i+2]=v.z; Bv[4*i+3]=v.w;
      float4 c=C4[i]; Cv[4*i]=c.x; Cv[4*i+1]=c.y; Cv[4*i+2]=c.z; Cv[4*i+3]=c.w;
    }
    float y0=0.f, y1=0.f;
    #pragma unroll
    for (int s=0;s<16;++s){
      float p = exp2f(dtv*a2[s]);
      h[s] = fmaf(p, h[s], q*Bv[s]);
      if (s & 1) y1 = fmaf(h[s], Cv[s], y1); else y0 = fmaf(h[s], Cv[s], y0);
    }
    float zv = xz[zoff];
    yout[off] = __float2bfloat16(fmaf(xv, dp, y0+y1) * (zv * sigmoidf_(zv)));
    off += DIN; boff += 48; zoff += 2*DIN;
  }
}

extern "C" void kernel_launch(void* const* d_in, const int* in_sizes, int n_in,
                              void* d_out, int out_size, void* d_ws, size_t ws_size,
                              hipStream_t stream)
{
  const float* z           = (const float*)d_in[0];
  const float* latent_g    = (const float*)d_in[1];
  const float* latent_b    = (const float*)d_in[2];
  const float* latent_w    = (const float*)d_in[3];
  const float* latent_bias = (const float*)d_in[4];
  const float* time_emb    = (const float*)d_in[5];
  const float* ln_g        = (const float*)d_in[6];
  const float* ln_b        = (const float*)d_in[7];
  const float* in_w        = (const float*)d_in[8];
  const float* in_b        = (const float*)d_in[9];
  const float* conv_w      = (const float*)d_in[10];
  const float* conv_b      = (const float*)d_in[11];
  const float* xp_w        = (const float*)d_in[12];
  const float* dt_w        = (const float*)d_in[13];
  const float* dt_b        = (const float*)d_in[14];
  const float* A_log       = (const float*)d_in[15];
  const float* Dp          = (const float*)d_in[16];
  const float* out_w       = (const float*)d_in[17];
  const float* out_b       = (const float*)d_in[18];
  const float* on_g        = (const float*)d_in[19];
  const float* on_b        = (const float*)d_in[20];
  const float* op_w        = (const float*)d_in[21];
  const float* op_b        = (const float*)d_in[22];
  float* out = (float*)d_out;

  // workspace layout: ~191 MB
  float* ws   = (float*)d_ws;
  float* base = ws;                                  // 16*256
  float* h    = base + NB*DMODEL;                    // NTOK*256
  float* xn   = h    + (size_t)NTOK*DMODEL;          // NTOK*256 fp32; doubles as xnbf (bf16 LN out)
  float* xz   = xn   + (size_t)NTOK*DMODEL;          // NTOK*1024 (xc half doubles as pstate, GCH*NB*DIN*16 = exact fit)
  float* xsb  = xz   + (size_t)NTOK*2*DIN;           // NTOK*512 fp32 (xs)
  float* dtb  = xsb  + (size_t)NTOK*DIN;             // NTOK*512 -> hstate (GCH*NB*DIN*16 floats = exact fit)
  float* dbc  = dtb  + (size_t)NTOK*DIN;             // NTOK*48
  __hip_bfloat16* ybf    = (__hip_bfloat16*)(dbc + (size_t)NTOK*48);   // NTOK*512 bf16
  __hip_bfloat16* inwbf  = ybf + (size_t)NTOK*DIN;                     // 4*1024*256
  __hip_bfloat16* outwbf = inwbf + (size_t)NLAYER*2*DIN*DMODEL;        // 4*256*512
  __hip_bfloat16* xpwbf  = outwbf + (size_t)NLAYER*DMODEL*DIN;         // 4*48*512
  __hip_bfloat16* opwbf  = xpwbf + (size_t)NLAYER*48*DIN;              // 64*256
  __hip_bfloat16* xnbf   = (__hip_bfloat16*)xn;
  float* hstate = dtb;

  // precast weights to bf16 (same work every call)
  castbf_kernel<<<(NLAYER*2*DIN*DMODEL)/256, 256, 0, stream>>>(in_w, inwbf, NLAYER*2*DIN*DMODEL);
  castbf_kernel<<<(NLAYER*DMODEL*DIN)/256, 256, 0, stream>>>(out_w, outwbf, NLAYER*DMODEL*DIN);
  castbf_kernel<<<(NLAYER*48*DIN)/256, 256, 0, stream>>>(xp_w, xpwbf, NLAYER*48*DIN);
  castbf_kernel<<<(NOUT*DMODEL)/256, 256, 0, stream>>>(op_w, opwbf, NOUT*DMODEL);

  latent_kernel<<<NB, 256, 0, stream>>>(z, latent_g, latent_b, latent_w, latent_bias, base);
  addtime_kernel<<<NTOK*DMODEL/256, 256, 0, stream>>>(base, time_emb, h);

  for (int i = 0; i < NLAYER; ++i) {
    ln_kernel<1><<<NTOK/4, 256, 0, stream>>>(h, ln_g + i*DMODEL, ln_b + i*DMODEL, xnbf);
    gemm_bf16<0><<<dim3(NTOK/128, (2*DIN)/128), 256, 0, stream>>>(
        xnbf, inwbf + (size_t)i*2*DIN*DMODEL, in_b + i*2*DIN, xz, NTOK, 2*DIN, DMODEL);
    conv_kernel<<<NTOK*DIN/256, 256, 0, stream>>>(
        xz, conv_w + i*DIN*KCONV, conv_b + i*DIN, xsb);
    gemm_smallm<3, 16><<<NTOK/64, 256, 0, stream>>>(
        xsb, xpwbf + (size_t)i*48*DIN, nullptr, dbc);
    scan1_kernel<<<GCH*NB*DIN/256, 256, 0, stream>>>(
        xsb, dbc, A_log + (size_t)i*DIN*DSTATE,
        dt_w + (size_t)i*DIN*DTRANK, dt_b + i*DIN, hstate, xz);
    scan2_kernel<<<NB*DIN*16/256, 256, 0, stream>>>(hstate, xz);
    scan3_kernel<<<GCH*NB*DIN/256, 256, 0, stream>>>(
        dbc, xz, A_log + (size_t)i*DIN*DSTATE,
        dt_w + (size_t)i*DIN*DTRANK, dt_b + i*DIN, Dp + i*DIN, hstate, xsb, ybf);
    gemm_bf16<1><<<dim3(NTOK/128, DMODEL/128), 256, 0, stream>>>(
        ybf, outwbf + (size_t)i*DMODEL*DIN, out_b + i*DMODEL, h, NTOK, DMODEL, DIN);
  }

  ln_kernel<0><<<NTOK/4, 256, 0, stream>>>(h, on_g, on_b, xn);
  gemm_smallm<4, 8><<<NTOK/64, 256, 0, stream>>>(xn, opwbf, op_b, out);
}

// Round 8
// 1123.477 us; speedup vs baseline: 1.0460x; 1.0460x over previous
//
#include <hip/hip_runtime.h>
#include <hip/hip_bf16.h>
#include <cstdint>
#include <cstddef>

#define NB 16
#define LATD 256
#define DMODEL 256
#define DIN 512
#define DSTATE 16
#define DTRANK 16
#define SEQ 1024
#define KCONV 4
#define NOUT 64
#define NLAYER 4
#define NTOK (NB*SEQ)   // 16384
#define GCH 32          // scan chunks
#define CLEN (SEQ/GCH)  // 32 steps per chunk
#define LOG2E 1.4426950408889634f

typedef __attribute__((ext_vector_type(8))) short short8;
typedef __attribute__((ext_vector_type(4))) float f32x4;

__device__ __forceinline__ float sigmoidf_(float x){ return 1.f/(1.f+__expf(-x)); }
__device__ __forceinline__ short bf16s(float x){ __hip_bfloat16 h = __float2bfloat16(x); return *(short*)&h; }
__device__ __forceinline__ float softplusf_(float x){ return (x > 20.f) ? x : __logf(1.f + __expf(x)); }

__device__ __forceinline__ void gl_lds16(const void* g, void* l) {
  __builtin_amdgcn_global_load_lds((const __attribute__((address_space(1))) void*)g,
                                   (__attribute__((address_space(3))) void*)l,
                                   16, 0, 0);
}

// ---------------- latent head: base = gelu(LN(z) @ latent_w.T + latent_bias) ----------------
__global__ void latent_kernel(const float* __restrict__ z,
                              const float* __restrict__ lg, const float* __restrict__ lb,
                              const float* __restrict__ lw, const float* __restrict__ lbias,
                              float* __restrict__ base)
{
  int b = blockIdx.x;          // 16
  int tid = threadIdx.x;       // 256
  __shared__ float zn[LATD];
  __shared__ float red[8];
  float v = z[b*LATD + tid];
  float s = v;
  #pragma unroll
  for (int off=32; off; off>>=1) s += __shfl_xor(s, off);
  if ((tid & 63)==0) red[tid>>6] = s;
  __syncthreads();
  float mu = (red[0]+red[1]+red[2]+red[3]) * (1.f/LATD);
  float dvi = v - mu;
  float s2 = dvi*dvi;
  #pragma unroll
  for (int off=32; off; off>>=1) s2 += __shfl_xor(s2, off);
  if ((tid & 63)==0) red[4 + (tid>>6)] = s2;
  __syncthreads();
  float var = (red[4]+red[5]+red[6]+red[7]) * (1.f/LATD);
  float rs = rsqrtf(var + 1e-5f);
  zn[tid] = dvi*rs*lg[tid] + lb[tid];
  __syncthreads();
  const float* wrow = &lw[(size_t)tid*LATD];
  float acc = lbias[tid];
  #pragma unroll 4
  for (int l=0; l<LATD; ++l) acc += zn[l]*wrow[l];
  float g = 0.5f*acc*(1.f + erff(acc*0.70710678118654752f));   // exact gelu
  base[b*DMODEL + tid] = g;
}

// ---------------- h = base[:,None,:] + time_emb[None] ----------------
__global__ void addtime_kernel(const float* __restrict__ base, const float* __restrict__ temb,
                               float* __restrict__ h)
{
  int idx = blockIdx.x*256 + threadIdx.x;  // over NTOK*DMODEL
  int dd = idx & (DMODEL-1);
  int t = (idx >> 8) & (SEQ-1);
  int bb = idx >> 18;
  h[idx] = base[bb*DMODEL + dd] + temb[t*DMODEL + dd];
}

// ---------------- per-token LayerNorm; 4 tokens/block (1 wave each); OUTBF=1 -> bf16 --------
template<int OUTBF>
__global__ void ln_kernel(const float* __restrict__ x, const float* __restrict__ g,
                          const float* __restrict__ b, void* __restrict__ outp)
{
  int n = blockIdx.x*4 + (threadIdx.x >> 6);
  int lane = threadIdx.x & 63;
  const float4 v = ((const float4*)&x[(size_t)n*DMODEL])[lane];
  float s = v.x+v.y+v.z+v.w;
  #pragma unroll
  for (int off=32; off; off>>=1) s += __shfl_xor(s, off);
  float mu = s * (1.f/DMODEL);
  float dx = v.x-mu, dy = v.y-mu, dz = v.z-mu, dw = v.w-mu;
  float s2 = dx*dx+dy*dy+dz*dz+dw*dw;
  #pragma unroll
  for (int off=32; off; off>>=1) s2 += __shfl_xor(s2, off);
  float rs = rsqrtf(s2*(1.f/DMODEL) + 1e-5f);
  const float4 gv = ((const float4*)g)[lane];
  const float4 bv = ((const float4*)b)[lane];
  float o0 = dx*rs*gv.x + bv.x;
  float o1 = dy*rs*gv.y + bv.y;
  float o2 = dz*rs*gv.z + bv.z;
  float o3 = dw*rs*gv.w + bv.w;
  if (OUTBF) {
    __hip_bfloat16* o = (__hip_bfloat16*)outp + (size_t)n*DMODEL + lane*4;
    o[0] = __float2bfloat16(o0); o[1] = __float2bfloat16(o1);
    o[2] = __float2bfloat16(o2); o[3] = __float2bfloat16(o3);
  } else {
    float4 o; o.x=o0; o.y=o1; o.z=o2; o.w=o3;
    ((float4*)((float*)outp + (size_t)n*DMODEL))[lane] = o;
  }
}

// ---------------- fp32 → bf16 cast ----------------
__global__ void castbf_kernel(const float* __restrict__ in, __hip_bfloat16* __restrict__ out, int n)
{
  int i = blockIdx.x*256 + threadIdx.x;
  if (i < n) out[i] = __float2bfloat16(in[i]);
}

// ---------------- bf16 MFMA GEMM: C[N,M] = A[N,K] @ W[M,K]^T (+bias) ----------
// OUTBF=1: C is bf16 (no ACCUM). OUTBF=0: C fp32, ACCUM optionally adds C.
template<int ACCUM, int OUTBF>
__global__ void gemm_bf16(const __hip_bfloat16* __restrict__ A,
                          const __hip_bfloat16* __restrict__ W,
                          const float* __restrict__ bias, void* __restrict__ Cp,
                          int N, int M, int K)
{
  __shared__ __hip_bfloat16 As[128*32];   // row-major, 32 bf16 (64B) per row, NO padding
  __shared__ __hip_bfloat16 Ws[128*32];
  int tid = threadIdx.x;
  int lane = tid & 63, w = tid >> 6;
  int wr = w >> 1, wc = w & 1;
  int n0 = blockIdx.x * 128, m0 = blockIdx.y * 128;
  int mrow = lane & 15, q = lane >> 4;
  f32x4 acc[4][4] = {};
  for (int k0 = 0; k0 < K; k0 += 32) {
    __syncthreads();
    #pragma unroll
    for (int j = 0; j < 2; ++j) {
      int c = (w*2 + j)*64 + lane;       // chunk 0..511 of the 8KB tile
      int r = c >> 2, cq = c & 3;        // row, 16B-chunk within row
      gl_lds16(A + (size_t)(n0 + r)*K + k0 + cq*8, (char*)As + (w*2+j)*1024);
      gl_lds16(W + (size_t)(m0 + r)*K + k0 + cq*8, (char*)Ws + (w*2+j)*1024);
    }
    __syncthreads();
    short8 af[4], bfr[4];
    #pragma unroll
    for (int t = 0; t < 4; ++t) {
      af[t]  = *(const short8*)(As + ((wr*64 + t*16 + mrow)*32 + q*8));
      bfr[t] = *(const short8*)(Ws + ((wc*64 + t*16 + mrow)*32 + q*8));
    }
    #pragma unroll
    for (int i = 0; i < 4; ++i)
      #pragma unroll
      for (int jj = 0; jj < 4; ++jj)
        acc[i][jj] = __builtin_amdgcn_mfma_f32_16x16x32_bf16(af[i], bfr[jj], acc[i][jj], 0, 0, 0);
  }
  int rq = lane >> 4, cl = lane & 15;
  #pragma unroll
  for (int i = 0; i < 4; ++i) {
    int n_base = n0 + wr*64 + i*16 + rq*4;
    #pragma unroll
    for (int jj = 0; jj < 4; ++jj) {
      int m = m0 + wc*64 + jj*16 + cl;
      float bv = bias ? bias[m] : 0.f;
      #pragma unroll
      for (int r = 0; r < 4; ++r) {
        size_t o = (size_t)(n_base + r)*M + m;
        float v = acc[i][jj][r] + bv;
        if (OUTBF) {
          ((__hip_bfloat16*)Cp)[o] = __float2bfloat16(v);
        } else {
          float* C = (float*)Cp;
          if (ACCUM) v += C[o];
          C[o] = v;
        }
      }
    }
  }
}

// ---------------- small-M MFMA GEMM: C[N, MT*16] = A[N, KT*32] @ W^T (+bias) ----------------
// AT = float (convert in-register) or __hip_bfloat16 (direct fragment load).
template<int MT, int KT, typename AT>
__global__ void gemm_smallm(const AT* __restrict__ A, const __hip_bfloat16* __restrict__ Wg,
                            const float* __restrict__ bias, float* __restrict__ C)
{
  constexpr int M = MT*16, K = KT*32;
  __shared__ __hip_bfloat16 Ws[MT*KT*64*8];
  int tid = threadIdx.x;
  #pragma unroll
  for (int c = tid; c < MT*KT*64; c += 256) {
    int lane = c & 63;
    int kt = (c >> 6) % KT;
    int mt = (c >> 6) / KT;
    int row = mt*16 + (lane & 15);
    int k   = kt*32 + (lane >> 4)*8;
    *(short8*)(Ws + (size_t)c*8) = *(const short8*)(Wg + (size_t)row*K + k);
  }
  __syncthreads();
  int lane = tid & 63, w = tid >> 6;
  int n0 = blockIdx.x*64 + w*16;
  int r = lane & 15, q = lane >> 4;
  const AT* Ap = A + (size_t)(n0 + r)*K + q*8;
  f32x4 acc[MT] = {};
  for (int kt = 0; kt < KT; ++kt) {
    short8 af;
    if constexpr (sizeof(AT) == 2) {
      af = *(const short8*)Ap;
    } else {
      float4 a0 = *(const float4*)(Ap);
      float4 a1 = *(const float4*)(Ap + 4);
      af[0]=bf16s(a0.x); af[1]=bf16s(a0.y); af[2]=bf16s(a0.z); af[3]=bf16s(a0.w);
      af[4]=bf16s(a1.x); af[5]=bf16s(a1.y); af[6]=bf16s(a1.z); af[7]=bf16s(a1.w);
    }
    Ap += 32;
    #pragma unroll
    for (int mt = 0; mt < MT; ++mt) {
      short8 bfr = *(const short8*)(Ws + ((size_t)(mt*KT + kt)*64 + lane)*8);
      acc[mt] = __builtin_amdgcn_mfma_f32_16x16x32_bf16(af, bfr, acc[mt], 0, 0, 0);
    }
  }
  #pragma unroll
  for (int mt = 0; mt < MT; ++mt) {
    float bv = bias ? bias[mt*16 + r] : 0.f;
    #pragma unroll
    for (int rr = 0; rr < 4; ++rr)
      C[(size_t)(n0 + q*4 + rr)*M + mt*16 + r] = acc[mt][rr] + bv;
  }
}

// ---------------- depthwise causal conv (K=4) + bias + SiLU; bf16 in/out, 2 d per thread ----
__global__ void conv_kernel(const __hip_bfloat16* __restrict__ xz, const float* __restrict__ cw,
                            const float* __restrict__ cb, __hip_bfloat16* __restrict__ xs)
{
  int idx = blockIdx.x*256 + threadIdx.x; // over NTOK*DIN/2
  int dp = idx & 255;
  int n = idx >> 8;
  int t = n & (SEQ-1);
  int d0 = dp*2;
  const float* w0 = &cw[d0*KCONV];
  const float* w1 = w0 + KCONV;
  float a0 = cb[d0], a1 = cb[d0+1];
  #pragma unroll
  for (int j = 0; j < KCONV; ++j) {
    if (t - j >= 0) {
      __hip_bfloat162 u = *(const __hip_bfloat162*)&xz[(size_t)(n-j)*(2*DIN) + d0];
      a0 = fmaf(__bfloat162float(u.x), w0[KCONV-1-j], a0);
      a1 = fmaf(__bfloat162float(u.y), w1[KCONV-1-j], a1);
    }
  }
  a0 = a0 * sigmoidf_(a0);
  a1 = a1 * sigmoidf_(a1);
  __hip_bfloat162 o;
  o.x = __float2bfloat16(a0); o.y = __float2bfloat16(a1);
  *(__hip_bfloat162*)&xs[(size_t)n*DIN + d0] = o;
}

// ================= chunked parallel scan (GCH=32, dt fused, dbc LDS-staged) =================
// Each block: constant (b,g); stages the chunk's dbc rows (CLEN*48 floats = 6 KB) into LDS.
__global__ void scan1_kernel(const __hip_bfloat16* __restrict__ xs, const float* __restrict__ dbc,
                             const float* __restrict__ Alog,
                             const float* __restrict__ dtw, const float* __restrict__ dtbias,
                             float* __restrict__ hstate, float* __restrict__ Pb)
{
  __shared__ float dl[CLEN*48];
  int tid = blockIdx.x*256 + threadIdx.x;  // GCH*NB*DIN = 262144
  int d = tid & (DIN-1);
  int b = (tid >> 9) & (NB-1);
  int g = tid >> 13;
  int t0 = g*CLEN;
  {
    const float* src = dbc + ((size_t)b*SEQ + t0)*48;
    for (int c = threadIdx.x; c < CLEN*48; c += 256) dl[c] = src[c];
  }
  float a2[16], h[16], P[16], wdt[16];
  const float4* A4 = (const float4*)&Alog[d*DSTATE];
  const float4* W4 = (const float4*)&dtw[d*DTRANK];
  #pragma unroll
  for (int i=0;i<4;++i){
    float4 v = A4[i];
    a2[4*i+0]=-__expf(v.x)*LOG2E; a2[4*i+1]=-__expf(v.y)*LOG2E;
    a2[4*i+2]=-__expf(v.z)*LOG2E; a2[4*i+3]=-__expf(v.w)*LOG2E;
    float4 wv = W4[i];
    wdt[4*i]=wv.x; wdt[4*i+1]=wv.y; wdt[4*i+2]=wv.z; wdt[4*i+3]=wv.w;
  }
  float bdt = dtbias[d];
  #pragma unroll
  for (int s=0;s<16;++s){ h[s]=0.f; P[s]=0.f; }   // P in log2 domain
  __syncthreads();
  size_t off = ((size_t)b*SEQ + t0)*DIN + d;
  for (int t=0;t<CLEN;++t){
    float xv = __bfloat162float(xs[off]);
    const float4* R4 = (const float4*)&dl[t*48];
    float4 r0 = R4[0], r1 = R4[1], r2 = R4[2], r3 = R4[3];
    float ac0 = fmaf(r0.x, wdt[0], bdt), ac1 = r0.y*wdt[1], ac2 = r0.z*wdt[2], ac3 = r0.w*wdt[3];
    ac0 = fmaf(r1.x, wdt[4], ac0); ac1 = fmaf(r1.y, wdt[5], ac1);
    ac2 = fmaf(r1.z, wdt[6], ac2); ac3 = fmaf(r1.w, wdt[7], ac3);
    ac0 = fmaf(r2.x, wdt[8], ac0); ac1 = fmaf(r2.y, wdt[9], ac1);
    ac2 = fmaf(r2.z, wdt[10], ac2); ac3 = fmaf(r2.w, wdt[11], ac3);
    ac0 = fmaf(r3.x, wdt[12], ac0); ac1 = fmaf(r3.y, wdt[13], ac1);
    ac2 = fmaf(r3.z, wdt[14], ac2); ac3 = fmaf(r3.w, wdt[15], ac3);
    float dtv = softplusf_((ac0+ac1)+(ac2+ac3));
    float q = dtv*xv;
    const float4* B4 = (const float4*)&dl[t*48 + DTRANK];
    float Bv[16];
    #pragma unroll
    for (int i=0;i<4;++i){ float4 v=B4[i]; Bv[4*i]=v.x; Bv[4*i+1]=v.y; Bv[4*i+2]=v.z; Bv[4*i+3]=v.w; }
    #pragma unroll
    for (int s=0;s<16;++s){
      float e = dtv*a2[s];
      float p = exp2f(e);
      P[s] += e;
      h[s] = fmaf(p, h[s], q*Bv[s]);
    }
    off += DIN;
  }
  float4* H4 = (float4*)&hstate[(size_t)tid*16];
  float4* P4 = (float4*)&Pb[(size_t)tid*16];
  #pragma unroll
  for (int i=0;i<4;++i) {
    H4[i] = make_float4(h[4*i],h[4*i+1],h[4*i+2],h[4*i+3]);
    P4[i] = make_float4(exp2f(P[4*i]),exp2f(P[4*i+1]),exp2f(P[4*i+2]),exp2f(P[4*i+3]));
  }
}

__global__ void scan2_kernel(float* __restrict__ hstate, const float* __restrict__ Pb)
{
  int tid = blockIdx.x*256 + threadIdx.x;  // NB*DIN*16 = 131072
  float hin = 0.f;
  size_t idx = (size_t)tid;
  for (int g=0; g<GCH; ++g){
    float P  = Pb[idx];
    float hl = hstate[idx];
    hstate[idx] = hin;               // becomes initial state for chunk g
    hin = fmaf(P, hin, hl);
    idx += (size_t)NB*DIN*16;
  }
}

__global__ void scan3_kernel(const float* __restrict__ dbc, const __hip_bfloat16* __restrict__ xz,
                             const float* __restrict__ Alog,
                             const float* __restrict__ dtw, const float* __restrict__ dtbias,
                             const float* __restrict__ Dp, const float* __restrict__ hstate,
                             const __hip_bfloat16* __restrict__ xs, __hip_bfloat16* __restrict__ yout)
{
  __shared__ float dl[CLEN*48];
  int tid = blockIdx.x*256 + threadIdx.x;  // 262144
  int d = tid & (DIN-1);
  int b = (tid >> 9) & (NB-1);
  int g = tid >> 13;
  int t0 = g*CLEN;
  {
    const float* src = dbc + ((size_t)b*SEQ + t0)*48;
    for (int c = threadIdx.x; c < CLEN*48; c += 256) dl[c] = src[c];
  }
  float a2[16], h[16], wdt[16];
  const float4* A4 = (const float4*)&Alog[d*DSTATE];
  const float4* W4 = (const float4*)&dtw[d*DTRANK];
  #pragma unroll
  for (int i=0;i<4;++i){
    float4 v = A4[i];
    a2[4*i+0]=-__expf(v.x)*LOG2E; a2[4*i+1]=-__expf(v.y)*LOG2E;
    a2[4*i+2]=-__expf(v.z)*LOG2E; a2[4*i+3]=-__expf(v.w)*LOG2E;
    float4 wv = W4[i];
    wdt[4*i]=wv.x; wdt[4*i+1]=wv.y; wdt[4*i+2]=wv.z; wdt[4*i+3]=wv.w;
  }
  float bdt = dtbias[d];
  const float4* H4 = (const float4*)&hstate[(size_t)tid*16];
  #pragma unroll
  for (int i=0;i<4;++i){ float4 v=H4[i]; h[4*i]=v.x; h[4*i+1]=v.y; h[4*i+2]=v.z; h[4*i+3]=v.w; }
  float dp = Dp[d];
  __syncthreads();
  size_t off  = ((size_t)b*SEQ + t0)*DIN + d;
  size_t zoff = ((size_t)b*SEQ + t0)*(2*DIN) + DIN + d;
  for (int t=0;t<CLEN;++t){
    float xv = __bfloat162float(xs[off]);
    const float4* R4 = (const float4*)&dl[t*48];
    float4 r0 = R4[0], r1 = R4[1], r2 = R4[2], r3 = R4[3];
    float ac0 = fmaf(r0.x, wdt[0], bdt), ac1 = r0.y*wdt[1], ac2 = r0.z*wdt[2], ac3 = r0.w*wdt[3];
    ac0 = fmaf(r1.x, wdt[4], ac0); ac1 = fmaf(r1.y, wdt[5], ac1);
    ac2 = fmaf(r1.z, wdt[6], ac2); ac3 = fmaf(r1.w, wdt[7], ac3);
    ac0 = fmaf(r2.x, wdt[8], ac0); ac1 = fmaf(r2.y, wdt[9], ac1);
    ac2 = fmaf(r2.z, wdt[10], ac2); ac3 = fmaf(r2.w, wdt[11], ac3);
    ac0 = fmaf(r3.x, wdt[12], ac0); ac1 = fmaf(r3.y, wdt[13], ac1);
    ac2 = fmaf(r3.z, wdt[14], ac2); ac3 = fmaf(r3.w, wdt[15], ac3);
    float dtv = softplusf_((ac0+ac1)+(ac2+ac3));
    float q = dtv*xv;
    const float4* B4 = (const float4*)&dl[t*48 + DTRANK];
    const float4* C4 = (const float4*)&dl[t*48 + DTRANK + DSTATE];
    float Bv[16], Cv[16];
    #pragma unroll
    for (int i=0;i<4;++i){
      float4 v=B4[i]; Bv[4*i]=v.x; Bv[4*i+1]=v.y; Bv[4*i+2]=v.z; Bv[4*i+3]=v.w;
      float4 c=C4[i]; Cv[4*i]=c.x; Cv[4*i+1]=c.y; Cv[4*i+2]=c.z; Cv[4*i+3]=c.w;
    }
    float y0=0.f, y1=0.f;
    #pragma unroll
    for (int s=0;s<16;++s){
      float p = exp2f(dtv*a2[s]);
      h[s] = fmaf(p, h[s], q*Bv[s]);
      if (s & 1) y1 = fmaf(h[s], Cv[s], y1); else y0 = fmaf(h[s], Cv[s], y0);
    }
    float zv = __bfloat162float(xz[zoff]);
    yout[off] = __float2bfloat16(fmaf(xv, dp, y0+y1) * (zv * sigmoidf_(zv)));
    off += DIN; zoff += 2*DIN;
  }
}

extern "C" void kernel_launch(void* const* d_in, const int* in_sizes, int n_in,
                              void* d_out, int out_size, void* d_ws, size_t ws_size,
                              hipStream_t stream)
{
  const float* z           = (const float*)d_in[0];
  const float* latent_g    = (const float*)d_in[1];
  const float* latent_b    = (const float*)d_in[2];
  const float* latent_w    = (const float*)d_in[3];
  const float* latent_bias = (const float*)d_in[4];
  const float* time_emb    = (const float*)d_in[5];
  const float* ln_g        = (const float*)d_in[6];
  const float* ln_b        = (const float*)d_in[7];
  const float* in_w        = (const float*)d_in[8];
  const float* in_b        = (const float*)d_in[9];
  const float* conv_w      = (const float*)d_in[10];
  const float* conv_b      = (const float*)d_in[11];
  const float* xp_w        = (const float*)d_in[12];
  const float* dt_w        = (const float*)d_in[13];
  const float* dt_b        = (const float*)d_in[14];
  const float* A_log       = (const float*)d_in[15];
  const float* Dp          = (const float*)d_in[16];
  const float* out_w       = (const float*)d_in[17];
  const float* out_b       = (const float*)d_in[18];
  const float* on_g        = (const float*)d_in[19];
  const float* on_b        = (const float*)d_in[20];
  const float* op_w        = (const float*)d_in[21];
  const float* op_b        = (const float*)d_in[22];
  float* out = (float*)d_out;

  // workspace layout
  float* ws   = (float*)d_ws;
  float* base = ws;                                  // 16*256
  float* h    = base + NB*DMODEL;                    // NTOK*256 fp32
  float* xn   = h    + (size_t)NTOK*DMODEL;          // NTOK*256 fp32; = xnbf (bf16 LN out) AND Pb (fp32, exact fit)
  float* xz   = xn   + (size_t)NTOK*DMODEL;          // region sized NTOK*1024 fp32; used as bf16 NTOK*1024
  float* xsb  = xz   + (size_t)NTOK*2*DIN;           // region NTOK*512 fp32; used as bf16 xs
  float* dtb  = xsb  + (size_t)NTOK*DIN;             // NTOK*512 fp32 -> hstate (16.8 MB used)
  float* dbc  = dtb  + (size_t)NTOK*DIN;             // NTOK*48 fp32
  __hip_bfloat16* ybf    = (__hip_bfloat16*)(dbc + (size_t)NTOK*48);   // NTOK*512 bf16
  __hip_bfloat16* inwbf  = ybf + (size_t)NTOK*DIN;                     // 4*1024*256
  __hip_bfloat16* outwbf = inwbf + (size_t)NLAYER*2*DIN*DMODEL;        // 4*256*512
  __hip_bfloat16* xpwbf  = outwbf + (size_t)NLAYER*DMODEL*DIN;         // 4*48*512
  __hip_bfloat16* opwbf  = xpwbf + (size_t)NLAYER*48*DIN;              // 64*256
  __hip_bfloat16* xnbf   = (__hip_bfloat16*)xn;
  __hip_bfloat16* xzbf   = (__hip_bfloat16*)xz;
  __hip_bfloat16* xsbf   = (__hip_bfloat16*)xsb;
  float* hstate = dtb;
  float* Pb     = xn;

  // precast weights to bf16 (same work every call)
  castbf_kernel<<<(NLAYER*2*DIN*DMODEL)/256, 256, 0, stream>>>(in_w, inwbf, NLAYER*2*DIN*DMODEL);
  castbf_kernel<<<(NLAYER*DMODEL*DIN)/256, 256, 0, stream>>>(out_w, outwbf, NLAYER*DMODEL*DIN);
  castbf_kernel<<<(NLAYER*48*DIN)/256, 256, 0, stream>>>(xp_w, xpwbf, NLAYER*48*DIN);
  castbf_kernel<<<(NOUT*DMODEL)/256, 256, 0, stream>>>(op_w, opwbf, NOUT*DMODEL);

  latent_kernel<<<NB, 256, 0, stream>>>(z, latent_g, latent_b, latent_w, latent_bias, base);
  addtime_kernel<<<NTOK*DMODEL/256, 256, 0, stream>>>(base, time_emb, h);

  for (int i = 0; i < NLAYER; ++i) {
    ln_kernel<1><<<NTOK/4, 256, 0, stream>>>(h, ln_g + i*DMODEL, ln_b + i*DMODEL, xnbf);
    gemm_bf16<0,1><<<dim3(NTOK/128, (2*DIN)/128), 256, 0, stream>>>(
        xnbf, inwbf + (size_t)i*2*DIN*DMODEL, in_b + i*2*DIN, xzbf, NTOK, 2*DIN, DMODEL);
    conv_kernel<<<NTOK*DIN/2/256, 256, 0, stream>>>(
        xzbf, conv_w + i*DIN*KCONV, conv_b + i*DIN, xsbf);
    gemm_smallm<3, 16, __hip_bfloat16><<<NTOK/64, 256, 0, stream>>>(
        xsbf, xpwbf + (size_t)i*48*DIN, nullptr, dbc);
    scan1_kernel<<<GCH*NB*DIN/256, 256, 0, stream>>>(
        xsbf, dbc, A_log + (size_t)i*DIN*DSTATE,
        dt_w + (size_t)i*DIN*DTRANK, dt_b + i*DIN, hstate, Pb);
    scan2_kernel<<<NB*DIN*16/256, 256, 0, stream>>>(hstate, Pb);
    scan3_kernel<<<GCH*NB*DIN/256, 256, 0, stream>>>(
        dbc, xzbf, A_log + (size_t)i*DIN*DSTATE,
        dt_w + (size_t)i*DIN*DTRANK, dt_b + i*DIN, Dp + i*DIN, hstate, xsbf, ybf);
    gemm_bf16<1,0><<<dim3(NTOK/128, DMODEL/128), 256, 0, stream>>>(
        ybf, outwbf + (size_t)i*DMODEL*DIN, out_b + i*DMODEL, h, NTOK, DMODEL, DIN);
  }

  ln_kernel<0><<<NTOK/4, 256, 0, stream>>>(h, on_g, on_b, xn);
  gemm_smallm<4, 8, float><<<NTOK/64, 256, 0, stream>>>(xn, opwbf, op_b, out);
}